// Round 1
// baseline (320.353 us; speedup 1.0000x reference)
//
#include <hip/hip_runtime.h>
#include <math.h>

#define NUM_ITEMS 10000
#define EMBED_DIM 64
#define MAX_HIST 200
#define BATCH 32
#define LEAKY 0.2f
#define W_USER 0.5f

// ---------------- Kernel A: WtI[i][g] = sum_f items[i][f] * W[f][g]; bdot[i] = sum_f bias[f]*items[i][f]
__global__ __launch_bounds__(256) void wti_kernel(const float* __restrict__ items,
                                                  const float* __restrict__ W,
                                                  const float* __restrict__ bias,
                                                  float* __restrict__ wti,
                                                  float* __restrict__ bdot) {
    int i = blockIdx.x * 4 + (threadIdx.x >> 6);
    int g = threadIdx.x & 63;
    if (i >= NUM_ITEMS) return;
    const float* irow = items + i * EMBED_DIM;
    float acc = 0.f;
#pragma unroll 8
    for (int f = 0; f < EMBED_DIM; ++f) {
        acc += irow[f] * W[f * EMBED_DIM + g];
    }
    wti[i * EMBED_DIM + g] = acc;
    float bv = bias[g] * irow[g];
#pragma unroll
    for (int o = 32; o > 0; o >>= 1) bv += __shfl_xor(bv, o, 64);
    if (g == 0) bdot[i] = bv;
}

// ---------------- Kernel B: gather hist[b] -> ws, compute user softmax scores -> ws
__global__ __launch_bounds__(256) void prep_kernel(const int* __restrict__ ids,
                                                   const int* __restrict__ lens,
                                                   const float* __restrict__ items,
                                                   const float* __restrict__ user,
                                                   float* __restrict__ hist_ws,
                                                   float* __restrict__ uscore_ws) {
    const int b = blockIdx.x;
    const int tid = threadIdx.x;
    __shared__ float sh_hist[MAX_HIST * EMBED_DIM];   // 51.2 KB
    __shared__ float red[8];

    const float4* items4 = (const float4*)items;
    float4* hist4 = (float4*)(hist_ws + (size_t)b * MAX_HIST * EMBED_DIM);
    float4* sh4 = (float4*)sh_hist;
    // gather 200*16 float4
    for (int idx = tid; idx < MAX_HIST * (EMBED_DIM / 4); idx += 256) {
        int n = idx >> 4;
        int f4 = idx & 15;
        int id = ids[b * MAX_HIST + n];
        float4 v = items4[id * (EMBED_DIM / 4) + f4];
        sh4[idx] = v;
        hist4[idx] = v;
    }
    __syncthreads();

    const int len = lens[b];
    float s = -INFINITY;
    if (tid < len) {  // len <= MAX_HIST
        float a0 = 0.f, a1 = 0.f;
#pragma unroll
        for (int f = 0; f < EMBED_DIM; f += 2) {
            a0 += user[f] * sh_hist[tid * EMBED_DIM + f];
            a1 += user[f + 1] * sh_hist[tid * EMBED_DIM + f + 1];
        }
        float a = a0 + a1;
        s = fmaxf(a, LEAKY * a);  // leaky_relu, slope<1
    }
    // block max
    float m = s;
#pragma unroll
    for (int o = 32; o > 0; o >>= 1) m = fmaxf(m, __shfl_xor(m, o, 64));
    if ((tid & 63) == 0) red[tid >> 6] = m;
    __syncthreads();
    m = fmaxf(fmaxf(red[0], red[1]), fmaxf(red[2], red[3]));

    float e = (tid < len) ? __expf(s - m) : 0.f;
    float t = e;
#pragma unroll
    for (int o = 32; o > 0; o >>= 1) t += __shfl_xor(t, o, 64);
    if ((tid & 63) == 0) red[4 + (tid >> 6)] = t;
    __syncthreads();
    float sum = red[4] + red[5] + red[6] + red[7];

    if (tid < MAX_HIST) {
        uscore_ws[b * MAX_HIST + tid] = (tid < len) ? (e / sum) : 0.f;
    }
}

// ---------------- Kernel C: fused item attention + combine
__global__ __launch_bounds__(256) void main_kernel(const float* __restrict__ items,
                                                   const float* __restrict__ wti,
                                                   const float* __restrict__ bdot,
                                                   const float* __restrict__ hist_ws,
                                                   const float* __restrict__ uscore_ws,
                                                   const int* __restrict__ lens,
                                                   float* __restrict__ out) {
    const int b = blockIdx.y;
    const int tid = threadIdx.x;
    const int i = blockIdx.x * 256 + tid;

    __shared__ float sh_hist[MAX_HIST * EMBED_DIM];  // 51.2 KB
    __shared__ float sh_us[MAX_HIST];

    const float4* src = (const float4*)(hist_ws + (size_t)b * MAX_HIST * EMBED_DIM);
    float4* dst = (float4*)sh_hist;
    for (int idx = tid; idx < MAX_HIST * (EMBED_DIM / 4); idx += 256) dst[idx] = src[idx];
    for (int idx = tid; idx < MAX_HIST; idx += 256) sh_us[idx] = uscore_ws[b * MAX_HIST + idx];
    __syncthreads();

    if (i >= NUM_ITEMS) return;

    float4 it[EMBED_DIM / 4], wt[EMBED_DIM / 4];
    const float4* ip = (const float4*)(items + (size_t)i * EMBED_DIM);
    const float4* wp = (const float4*)(wti + (size_t)i * EMBED_DIM);
#pragma unroll
    for (int k = 0; k < EMBED_DIM / 4; ++k) { it[k] = ip[k]; wt[k] = wp[k]; }

    const int len = lens[b];
    float m = -INFINITY, se = 0.f, acc = 0.f, accU = 0.f;
    const float4* h4 = (const float4*)sh_hist;

    for (int n = 0; n < len; ++n) {
        const float4* hv = h4 + n * (EMBED_DIM / 4);
        float s0 = 0.f, s1 = 0.f, h0 = 0.f, h1 = 0.f;
#pragma unroll
        for (int k = 0; k < EMBED_DIM / 4; k += 2) {
            float4 a = hv[k];
            float4 c = hv[k + 1];
            s0 += it[k].x * a.x + it[k].y * a.y + it[k].z * a.z + it[k].w * a.w;
            h0 += wt[k].x * a.x + wt[k].y * a.y + wt[k].z * a.z + wt[k].w * a.w;
            s1 += it[k + 1].x * c.x + it[k + 1].y * c.y + it[k + 1].z * c.z + it[k + 1].w * c.w;
            h1 += wt[k + 1].x * c.x + wt[k + 1].y * c.y + wt[k + 1].z * c.z + wt[k + 1].w * c.w;
        }
        float s = s0 + s1;
        float h = h0 + h1;
        s = fmaxf(s, LEAKY * s);              // leaky_relu (slope < 1)
        float mn = fmaxf(m, s);               // online softmax, branchless
        float cc = __expf(m - mn);            // first iter: exp(-inf)=0
        float e = __expf(s - mn);
        se = se * cc + e;
        acc = acc * cc + e * h;
        accU += sh_us[n] * h;
        m = mn;
    }

    out[(size_t)b * NUM_ITEMS + i] = (1.0f - W_USER) * (acc / se) + W_USER * accU + bdot[i];
}

extern "C" void kernel_launch(void* const* d_in, const int* in_sizes, int n_in,
                              void* d_out, int out_size, void* d_ws, size_t ws_size,
                              hipStream_t stream) {
    const int* ids = (const int*)d_in[0];
    const int* lens = (const int*)d_in[1];
    const float* items = (const float*)d_in[2];
    const float* user = (const float*)d_in[3];
    const float* W = (const float*)d_in[4];
    const float* bias = (const float*)d_in[5];
    float* out = (float*)d_out;

    float* wti = (float*)d_ws;                               // 10000*64
    float* bdot = wti + NUM_ITEMS * EMBED_DIM;               // 10000
    float* hist = bdot + NUM_ITEMS;                          // 32*200*64
    float* uscore = hist + BATCH * MAX_HIST * EMBED_DIM;     // 32*200

    wti_kernel<<<(NUM_ITEMS + 3) / 4, 256, 0, stream>>>(items, W, bias, wti, bdot);
    prep_kernel<<<BATCH, 256, 0, stream>>>(ids, lens, items, user, hist, uscore);

    dim3 grid((NUM_ITEMS + 255) / 256, BATCH);
    main_kernel<<<grid, 256, 0, stream>>>(items, wti, bdot, hist, uscore, lens, out);
}

// Round 2
// 74.031 us; speedup vs baseline: 4.3273x; 4.3273x over previous
//
#include <hip/hip_runtime.h>
#include <hip/hip_bf16.h>
#include <math.h>

#define NUM_ITEMS 10000
#define EMBED_DIM 64
#define MAX_HIST 200
#define NPAD 208          // MAX_HIST padded to multiple of 16
#define BATCH 32
#define LEAKY 0.2f
#define W_USER 0.5f

typedef short bf16x8 __attribute__((ext_vector_type(8)));
typedef float f32x4 __attribute__((ext_vector_type(4)));

__device__ __forceinline__ unsigned short f2bf(float f) {
    __hip_bfloat16 h = __float2bfloat16(f);
    return __builtin_bit_cast(unsigned short, h);
}

// ---------------- Kernel A: WtI (bf16), items (bf16), bdot
// wti[i][g] = sum_f items[i][f] * W[f][g]   (== items @ fc_weight, verified round 1)
// bdot[i]   = sum_g bias[g] * items[i][g]
__global__ __launch_bounds__(256) void wti_kernel(const float* __restrict__ items,
                                                  const float* __restrict__ W,
                                                  const float* __restrict__ bias,
                                                  unsigned short* __restrict__ wti_bf,
                                                  unsigned short* __restrict__ items_bf,
                                                  float* __restrict__ bdot) {
    __shared__ float shW[EMBED_DIM * EMBED_DIM];  // 16 KB
    const int tid = threadIdx.x;
    for (int idx = tid; idx < EMBED_DIM * EMBED_DIM; idx += 256) shW[idx] = W[idx];
    __syncthreads();

    const int i = blockIdx.x * 4 + (tid >> 6);    // 2500*4 == 10000 exactly
    const int g = tid & 63;
    const float* irow = items + i * EMBED_DIM;

    float acc = 0.f;
#pragma unroll
    for (int f = 0; f < EMBED_DIM; ++f) acc += irow[f] * shW[f * EMBED_DIM + g];

    wti_bf[i * EMBED_DIM + g] = f2bf(acc);
    items_bf[i * EMBED_DIM + g] = f2bf(irow[g]);

    float bv = bias[g] * irow[g];
#pragma unroll
    for (int o = 32; o > 0; o >>= 1) bv += __shfl_xor(bv, o, 64);
    if (g == 0) bdot[i] = bv;
}

// ---------------- Kernel B: gather hist -> bf16 (padded to NPAD rows), user softmax -> us_ws
__global__ __launch_bounds__(256) void prep_kernel(const int* __restrict__ ids,
                                                   const int* __restrict__ lens,
                                                   const float* __restrict__ items,
                                                   const float* __restrict__ user,
                                                   unsigned short* __restrict__ hist_bf,
                                                   float* __restrict__ us_ws) {
    const int b = blockIdx.x;
    const int tid = threadIdx.x;
    __shared__ float red[8];

    // gather + convert: NPAD rows x 8 chunks of 8 bf16
    for (int idx = tid; idx < NPAD * 8; idx += 256) {
        const int n = idx >> 3, q = idx & 7;
        bf16x8 v = (bf16x8)0;
        if (n < MAX_HIST) {
            const int id = ids[b * MAX_HIST + n];
            const float4* p = (const float4*)(items + id * EMBED_DIM + q * 8);
            float4 v0 = p[0], v1 = p[1];
            v[0] = (short)f2bf(v0.x); v[1] = (short)f2bf(v0.y);
            v[2] = (short)f2bf(v0.z); v[3] = (short)f2bf(v0.w);
            v[4] = (short)f2bf(v1.x); v[5] = (short)f2bf(v1.y);
            v[6] = (short)f2bf(v1.z); v[7] = (short)f2bf(v1.w);
        }
        *(bf16x8*)(hist_bf + (size_t)(b * NPAD + n) * EMBED_DIM + q * 8) = v;
    }

    // user-perspective scores (fp32)
    const int len = lens[b];
    float s = -INFINITY;
    if (tid < len) {
        const int id = ids[b * MAX_HIST + tid];
        const float* h = items + id * EMBED_DIM;
        float a0 = 0.f, a1 = 0.f;
#pragma unroll
        for (int f = 0; f < EMBED_DIM; f += 2) {
            a0 += user[f] * h[f];
            a1 += user[f + 1] * h[f + 1];
        }
        float a = a0 + a1;
        s = fmaxf(a, LEAKY * a);
    }
    float m = s;
#pragma unroll
    for (int o = 32; o > 0; o >>= 1) m = fmaxf(m, __shfl_xor(m, o, 64));
    if ((tid & 63) == 0) red[tid >> 6] = m;
    __syncthreads();
    m = fmaxf(fmaxf(red[0], red[1]), fmaxf(red[2], red[3]));

    float e = (tid < len) ? __expf(s - m) : 0.f;
    float t = e;
#pragma unroll
    for (int o = 32; o > 0; o >>= 1) t += __shfl_xor(t, o, 64);
    if ((tid & 63) == 0) red[4 + (tid >> 6)] = t;
    __syncthreads();
    const float sum = red[4] + red[5] + red[6] + red[7];

    if (tid < NPAD) us_ws[b * NPAD + tid] = (tid < len) ? (e / sum) : 0.f;
}

// ---------------- Kernel C: MFMA main — per wave: 16 items x all NPAD n, batch b
__global__ __launch_bounds__(256) void main_kernel(const unsigned short* __restrict__ items_bf,
                                                   const unsigned short* __restrict__ wti_bf,
                                                   const float* __restrict__ bdot,
                                                   const unsigned short* __restrict__ hist_bf,
                                                   const float* __restrict__ us_ws,
                                                   const int* __restrict__ lens,
                                                   float* __restrict__ out) {
    const int b = blockIdx.y;
    const int tid = threadIdx.x;
    const int lane = tid & 63;
    const int w = tid >> 6;

    __shared__ __align__(16) unsigned short sh_hist[NPAD * EMBED_DIM];  // 26.6 KB, swizzled
    __shared__ float sh_us[NPAD];

    // stage hist (XOR-swizzle: row stride = 128 B -> 32-way conflict without it)
    const float4* src = (const float4*)(hist_bf + (size_t)b * NPAD * EMBED_DIM);
    for (int c = tid; c < NPAD * 8; c += 256) {
        const int n = c >> 3, q = c & 7;
        float4 v = src[c];
        const int byte = (n * 128 + q * 16) ^ ((n & 7) << 4);
        *(float4*)((char*)sh_hist + byte) = v;
    }
    for (int c = tid; c < NPAD; c += 256) sh_us[c] = us_ws[b * NPAD + c];
    __syncthreads();

    const int i0 = blockIdx.x * 64 + w * 16;
    if (i0 >= NUM_ITEMS) return;  // 10000 % 16 == 0: groups fully valid or fully dead

    const int c16 = lane & 15;    // item column within group
    const int g = lane >> 4;      // k-block / n-subrow group
    const int i = i0 + c16;

    // B-fragments: row = lane&15, k = 32*kk + 8*(lane>>4) .. +7 (contiguous)
    bf16x8 itf0 = *(const bf16x8*)(items_bf + (size_t)i * 64 + g * 8);
    bf16x8 itf1 = *(const bf16x8*)(items_bf + (size_t)i * 64 + 32 + g * 8);
    bf16x8 wtf0 = *(const bf16x8*)(wti_bf + (size_t)i * 64 + g * 8);
    bf16x8 wtf1 = *(const bf16x8*)(wti_bf + (size_t)i * 64 + 32 + g * 8);

    f32x4 accS[13], accH[13];
#pragma unroll
    for (int t = 0; t < 13; ++t) { accS[t] = (f32x4)0.f; accH[t] = (f32x4)0.f; }

#pragma unroll
    for (int t = 0; t < 13; ++t) {
        const int n = t * 16 + c16;                 // A-frag row (history index)
        const int base = n * 128;
        const int sw = (n & 7) << 4;
        bf16x8 a0 = *(const bf16x8*)((const char*)sh_hist + ((base + g * 16) ^ sw));
        bf16x8 a1 = *(const bf16x8*)((const char*)sh_hist + ((base + 64 + g * 16) ^ sw));
        accS[t] = __builtin_amdgcn_mfma_f32_16x16x32_bf16(a0, itf0, accS[t], 0, 0, 0);
        accS[t] = __builtin_amdgcn_mfma_f32_16x16x32_bf16(a1, itf1, accS[t], 0, 0, 0);
        accH[t] = __builtin_amdgcn_mfma_f32_16x16x32_bf16(a0, wtf0, accH[t], 0, 0, 0);
        accH[t] = __builtin_amdgcn_mfma_f32_16x16x32_bf16(a1, wtf1, accH[t], 0, 0, 0);
    }

    // C/D layout: col(item) = lane&15, row(n) = 16t + 4g + j
    const int len = lens[b];
    float m = -INFINITY;
#pragma unroll
    for (int t = 0; t < 13; ++t) {
        const int nb = t * 16 + g * 4;
#pragma unroll
        for (int j = 0; j < 4; ++j) {
            float s = accS[t][j];
            s = fmaxf(s, LEAKY * s);                 // leaky_relu, slope < 1
            s = (nb + j < len) ? s : -INFINITY;      // mask
            accS[t][j] = s;
            m = fmaxf(m, s);
        }
    }
    m = fmaxf(m, __shfl_xor(m, 16, 64));
    m = fmaxf(m, __shfl_xor(m, 32, 64));             // len>=1 -> m finite

    float Se = 0.f, Sh = 0.f, Su = 0.f;
#pragma unroll
    for (int t = 0; t < 13; ++t) {
        const float4 usv = *(const float4*)(sh_us + t * 16 + g * 4);
        const float us[4] = {usv.x, usv.y, usv.z, usv.w};
#pragma unroll
        for (int j = 0; j < 4; ++j) {
            const float e = __expf(accS[t][j] - m);  // masked: exp(-inf)=0
            const float h = accH[t][j];
            Se += e;
            Sh = fmaf(e, h, Sh);
            Su = fmaf(us[j], h, Su);
        }
    }
    Se += __shfl_xor(Se, 16, 64); Se += __shfl_xor(Se, 32, 64);
    Sh += __shfl_xor(Sh, 16, 64); Sh += __shfl_xor(Sh, 32, 64);
    Su += __shfl_xor(Su, 16, 64); Su += __shfl_xor(Su, 32, 64);

    if (g == 0)
        out[(size_t)b * NUM_ITEMS + i] =
            (1.0f - W_USER) * (Sh / Se) + W_USER * Su + bdot[i];
}

extern "C" void kernel_launch(void* const* d_in, const int* in_sizes, int n_in,
                              void* d_out, int out_size, void* d_ws, size_t ws_size,
                              hipStream_t stream) {
    const int* ids = (const int*)d_in[0];
    const int* lens = (const int*)d_in[1];
    const float* items = (const float*)d_in[2];
    const float* user = (const float*)d_in[3];
    const float* W = (const float*)d_in[4];
    const float* bias = (const float*)d_in[5];
    float* out = (float*)d_out;

    char* p = (char*)d_ws;
    unsigned short* items_bf = (unsigned short*)p; p += (size_t)NUM_ITEMS * EMBED_DIM * 2;
    unsigned short* wti_bf   = (unsigned short*)p; p += (size_t)NUM_ITEMS * EMBED_DIM * 2;
    float* bdot              = (float*)p;          p += (size_t)NUM_ITEMS * 4;
    unsigned short* hist_bf  = (unsigned short*)p; p += (size_t)BATCH * NPAD * EMBED_DIM * 2;
    float* us_ws             = (float*)p;          p += (size_t)BATCH * NPAD * 4;

    wti_kernel<<<NUM_ITEMS / 4, 256, 0, stream>>>(items, W, bias, wti_bf, items_bf, bdot);
    prep_kernel<<<BATCH, 256, 0, stream>>>(ids, lens, items, user, hist_bf, us_ws);

    dim3 grid((NUM_ITEMS + 63) / 64, BATCH);
    main_kernel<<<grid, 256, 0, stream>>>(items_bf, wti_bf, bdot, hist_bf, us_ws, lens, out);
}

// Round 3
// 41.548 us; speedup vs baseline: 7.7104x; 1.7818x over previous
//
#include <hip/hip_runtime.h>
#include <hip/hip_bf16.h>
#include <math.h>

#define NUM_ITEMS 10000
#define EMBED_DIM 64
#define MAX_HIST 200
#define NPAD 208          // MAX_HIST padded to multiple of 16
#define BATCH 32
#define LEAKY 0.2f
#define W_USER 0.5f
#define LOG2E 1.4426950408889634f
#define M_INIT (-1e30f)

typedef short bf16x8 __attribute__((ext_vector_type(8)));
typedef float f32x4 __attribute__((ext_vector_type(4)));

__device__ __forceinline__ unsigned short f2bf(float f) {
    __hip_bfloat16 h = __float2bfloat16(f);
    return __builtin_bit_cast(unsigned short, h);
}

__device__ __forceinline__ float fexp2(float x) {
#if __has_builtin(__builtin_amdgcn_exp2f)
    return __builtin_amdgcn_exp2f(x);
#else
    return exp2f(x);
#endif
}

// ---------------- Kernel P (fused prep):
// blocks [0, NUM_ITEMS/4):      wti_bf = bf16(items@W), items_att_bf = bf16(items*log2e), bdot
// blocks [NUM_ITEMS/4, +BATCH): hist gather -> bf16 (NPAD rows), user softmax -> us_ws
__global__ __launch_bounds__(256) void prep_kernel(const int* __restrict__ ids,
                                                   const int* __restrict__ lens,
                                                   const float* __restrict__ items,
                                                   const float* __restrict__ user,
                                                   const float* __restrict__ W,
                                                   const float* __restrict__ bias,
                                                   unsigned short* __restrict__ items_att_bf,
                                                   unsigned short* __restrict__ wti_bf,
                                                   float* __restrict__ bdot,
                                                   unsigned short* __restrict__ hist_bf,
                                                   float* __restrict__ us_ws) {
    const int tid = threadIdx.x;
    __shared__ float shW[EMBED_DIM * EMBED_DIM];  // 16 KB (wti part only)
    __shared__ float red[8];

    if (blockIdx.x < NUM_ITEMS / 4) {
        // ---- WtI part ----
        for (int idx = tid; idx < EMBED_DIM * EMBED_DIM; idx += 256) shW[idx] = W[idx];
        __syncthreads();

        const int i = blockIdx.x * 4 + (tid >> 6);
        const int g = tid & 63;
        const float* irow = items + i * EMBED_DIM;

        float acc = 0.f;
#pragma unroll
        for (int f = 0; f < EMBED_DIM; ++f) acc += irow[f] * shW[f * EMBED_DIM + g];

        wti_bf[i * EMBED_DIM + g] = f2bf(acc);
        // pre-scale attention operand by log2(e): leaky is positively homogeneous,
        // so exp2(log2e * leaky(s)) == exp(leaky(s)) exactly
        items_att_bf[i * EMBED_DIM + g] = f2bf(irow[g] * LOG2E);

        float bv = bias[g] * irow[g];
#pragma unroll
        for (int o = 32; o > 0; o >>= 1) bv += __shfl_xor(bv, o, 64);
        if (g == 0) bdot[i] = bv;
    } else {
        // ---- hist gather + user softmax part ----
        const int b = blockIdx.x - NUM_ITEMS / 4;

        for (int idx = tid; idx < NPAD * 8; idx += 256) {
            const int n = idx >> 3, q = idx & 7;
            bf16x8 v = (bf16x8)0;
            if (n < MAX_HIST) {
                const int id = ids[b * MAX_HIST + n];
                const float4* p = (const float4*)(items + id * EMBED_DIM + q * 8);
                float4 v0 = p[0], v1 = p[1];
                v[0] = (short)f2bf(v0.x); v[1] = (short)f2bf(v0.y);
                v[2] = (short)f2bf(v0.z); v[3] = (short)f2bf(v0.w);
                v[4] = (short)f2bf(v1.x); v[5] = (short)f2bf(v1.y);
                v[6] = (short)f2bf(v1.z); v[7] = (short)f2bf(v1.w);
            }
            *(bf16x8*)(hist_bf + (size_t)(b * NPAD + n) * EMBED_DIM + q * 8) = v;
        }

        const int len = lens[b];
        float s = -INFINITY;
        if (tid < len) {
            const int id = ids[b * MAX_HIST + tid];
            const float* h = items + id * EMBED_DIM;
            float a0 = 0.f, a1 = 0.f;
#pragma unroll
            for (int f = 0; f < EMBED_DIM; f += 2) {
                a0 += user[f] * h[f];
                a1 += user[f + 1] * h[f + 1];
            }
            float a = a0 + a1;
            s = fmaxf(a, LEAKY * a);
        }
        float m = s;
#pragma unroll
        for (int o = 32; o > 0; o >>= 1) m = fmaxf(m, __shfl_xor(m, o, 64));
        if ((tid & 63) == 0) red[tid >> 6] = m;
        __syncthreads();
        m = fmaxf(fmaxf(red[0], red[1]), fmaxf(red[2], red[3]));

        float e = (tid < len) ? __expf(s - m) : 0.f;
        float t = e;
#pragma unroll
        for (int o = 32; o > 0; o >>= 1) t += __shfl_xor(t, o, 64);
        if ((tid & 63) == 0) red[4 + (tid >> 6)] = t;
        __syncthreads();
        const float sum = red[4] + red[5] + red[6] + red[7];

        if (tid < NPAD) us_ws[b * NPAD + tid] = (tid < len) ? (e / sum) : 0.f;
    }
}

// ---------------- Kernel C: MFMA main, len-adaptive online softmax
__global__ __launch_bounds__(256) void main_kernel(const unsigned short* __restrict__ items_att_bf,
                                                   const unsigned short* __restrict__ wti_bf,
                                                   const float* __restrict__ bdot,
                                                   const unsigned short* __restrict__ hist_bf,
                                                   const float* __restrict__ us_ws,
                                                   const int* __restrict__ lens,
                                                   float* __restrict__ out) {
    const int b = blockIdx.y;
    const int tid = threadIdx.x;
    const int lane = tid & 63;
    const int w = tid >> 6;

    __shared__ __align__(16) unsigned short sh_hist[NPAD * EMBED_DIM];  // 26.6 KB, swizzled
    __shared__ float sh_us[NPAD];

    const int len = lens[b];                 // block-uniform
    const int ntiles = (len + 15) >> 4;      // 1..13

    // stage only the rows we need (XOR-swizzle: row stride 128 B)
    const float4* src = (const float4*)(hist_bf + (size_t)b * NPAD * EMBED_DIM);
    const int nf4 = ntiles * 16 * 8;
    for (int c = tid; c < nf4; c += 256) {
        const int n = c >> 3, q = c & 7;
        float4 v = src[c];
        const int byte = (n * 128 + q * 16) ^ ((n & 7) << 4);
        *(float4*)((char*)sh_hist + byte) = v;
    }
    for (int c = tid; c < ntiles * 16; c += 256) sh_us[c] = us_ws[b * NPAD + c];
    __syncthreads();

    const int i0 = blockIdx.x * 64 + w * 16;
    if (i0 >= NUM_ITEMS) return;

    const int c16 = lane & 15;   // item column within 16-group
    const int g = lane >> 4;     // k-chunk / n-subrow group
    const int i = i0 + c16;

    // B-fragments (row = lane&15, k = 32*kk + 8*g .. +7)
    bf16x8 itf0 = *(const bf16x8*)(items_att_bf + (size_t)i * 64 + g * 8);
    bf16x8 itf1 = *(const bf16x8*)(items_att_bf + (size_t)i * 64 + 32 + g * 8);
    bf16x8 wtf0 = *(const bf16x8*)(wti_bf + (size_t)i * 64 + g * 8);
    bf16x8 wtf1 = *(const bf16x8*)(wti_bf + (size_t)i * 64 + 32 + g * 8);

    float m = M_INIT, Se = 0.f, Sh = 0.f, Su = 0.f;

#define TILE_BODY(T, MASKED)                                                              \
    {                                                                                     \
        const int n = (T) * 16 + c16;                                                     \
        const int base = n * 128, sw = (n & 7) << 4;                                      \
        bf16x8 a0 = *(const bf16x8*)((const char*)sh_hist + ((base + g * 16) ^ sw));      \
        bf16x8 a1 = *(const bf16x8*)((const char*)sh_hist + ((base + 64 + g * 16) ^ sw)); \
        f32x4 S = (f32x4)0.f, H = (f32x4)0.f;                                             \
        S = __builtin_amdgcn_mfma_f32_16x16x32_bf16(a0, itf0, S, 0, 0, 0);                \
        S = __builtin_amdgcn_mfma_f32_16x16x32_bf16(a1, itf1, S, 0, 0, 0);                \
        H = __builtin_amdgcn_mfma_f32_16x16x32_bf16(a0, wtf0, H, 0, 0, 0);                \
        H = __builtin_amdgcn_mfma_f32_16x16x32_bf16(a1, wtf1, H, 0, 0, 0);                \
        const int nb = (T) * 16 + g * 4;                                                  \
        float s0 = fmaxf(S[0], LEAKY * S[0]);                                             \
        float s1 = fmaxf(S[1], LEAKY * S[1]);                                             \
        float s2 = fmaxf(S[2], LEAKY * S[2]);                                             \
        float s3 = fmaxf(S[3], LEAKY * S[3]);                                             \
        if (MASKED) {                                                                     \
            s0 = (nb + 0 < len) ? s0 : -INFINITY;                                         \
            s1 = (nb + 1 < len) ? s1 : -INFINITY;                                         \
            s2 = (nb + 2 < len) ? s2 : -INFINITY;                                         \
            s3 = (nb + 3 < len) ? s3 : -INFINITY;                                         \
        }                                                                                 \
        const float mn = fmaxf(fmaxf(fmaxf(s0, s1), fmaxf(s2, s3)), m);                   \
        const float cc = fexp2(m - mn);                                                   \
        const float e0 = fexp2(s0 - mn), e1 = fexp2(s1 - mn);                             \
        const float e2 = fexp2(s2 - mn), e3 = fexp2(s3 - mn);                             \
        const float4 usv = *(const float4*)(sh_us + (T) * 16 + g * 4);                    \
        Se = fmaf(Se, cc, (e0 + e1) + (e2 + e3));                                         \
        Sh = fmaf(Sh, cc, fmaf(e0, H[0], fmaf(e1, H[1], fmaf(e2, H[2], e3 * H[3]))));     \
        Su = fmaf(usv.x, H[0], fmaf(usv.y, H[1], fmaf(usv.z, H[2], fmaf(usv.w, H[3], Su)))); \
        m = mn;                                                                           \
    }

    // full tiles (unmasked), then one masked final tile (len>=1 -> ntiles>=1)
    for (int t = 0; t < ntiles - 1; ++t) TILE_BODY(t, 0)
    TILE_BODY(ntiles - 1, 1)
#undef TILE_BODY

    // cross-lane flash combine over the 4 n-groups (lanes i, i+16, i+32, i+48)
#pragma unroll
    for (int off = 16; off <= 32; off <<= 1) {
        const float m2 = __shfl_xor(m, off, 64);
        const float Se2 = __shfl_xor(Se, off, 64);
        const float Sh2 = __shfl_xor(Sh, off, 64);
        const float mn = fmaxf(m, m2);           // m always finite (>= M_INIT)
        const float c1 = fexp2(m - mn);
        const float c2 = fexp2(m2 - mn);
        Se = Se * c1 + Se2 * c2;
        Sh = Sh * c1 + Sh2 * c2;
        m = mn;
    }
    Su += __shfl_xor(Su, 16, 64);
    Su += __shfl_xor(Su, 32, 64);

    if (g == 0)
        out[(size_t)b * NUM_ITEMS + i] =
            (1.0f - W_USER) * (Sh / Se) + W_USER * Su + bdot[i];
}

extern "C" void kernel_launch(void* const* d_in, const int* in_sizes, int n_in,
                              void* d_out, int out_size, void* d_ws, size_t ws_size,
                              hipStream_t stream) {
    const int* ids = (const int*)d_in[0];
    const int* lens = (const int*)d_in[1];
    const float* items = (const float*)d_in[2];
    const float* user = (const float*)d_in[3];
    const float* W = (const float*)d_in[4];
    const float* bias = (const float*)d_in[5];
    float* out = (float*)d_out;

    char* p = (char*)d_ws;
    unsigned short* items_att_bf = (unsigned short*)p; p += (size_t)NUM_ITEMS * EMBED_DIM * 2;
    unsigned short* wti_bf       = (unsigned short*)p; p += (size_t)NUM_ITEMS * EMBED_DIM * 2;
    float* bdot                  = (float*)p;          p += (size_t)NUM_ITEMS * 4;
    unsigned short* hist_bf      = (unsigned short*)p; p += (size_t)BATCH * NPAD * EMBED_DIM * 2;
    float* us_ws                 = (float*)p;          p += (size_t)BATCH * NPAD * 4;

    prep_kernel<<<NUM_ITEMS / 4 + BATCH, 256, 0, stream>>>(ids, lens, items, user, W, bias,
                                                           items_att_bf, wti_bf, bdot,
                                                           hist_bf, us_ws);

    dim3 grid((NUM_ITEMS + 63) / 64, BATCH);
    main_kernel<<<grid, 256, 0, stream>>>(items_att_bf, wti_bf, bdot, hist_bf, us_ws, lens, out);
}